// Round 13
// baseline (265.261 us; speedup 1.0000x reference)
//
#include <hip/hip_runtime.h>
#include <stdint.h>

// HyperLatticeBlock: B=2,S=1024,D=1024,L=48,K=4  (tokens T=2048)
// gate(top4+pack) -> wconvT(W->Wt bf16 [e][d]) -> expert GEMM (3-deep LDS ring, counted vmcnt)
//   -> combine -> out_proj -> LN
#define TT 2048
#define DD 1024
#define LL 48
#define SENT (LL * 256)   // sentinel selp row (zeroed)

typedef __attribute__((ext_vector_type(8))) short short8;
typedef __attribute__((ext_vector_type(4))) float f32x4;

static __device__ __forceinline__ unsigned int f2bf(float f) {
  union { float f; unsigned int u; } v; v.f = f;
  return (v.u + 0x7FFFu + ((v.u >> 16) & 1u)) >> 16;   // RNE f32->bf16 bits
}
static __device__ __forceinline__ unsigned int pack2(float a, float b) {
  return f2bf(a) | (f2bf(b) << 16);
}

typedef __attribute__((address_space(1))) const void* as1_t;
typedef __attribute__((address_space(3))) void* as3_t;
static __device__ __forceinline__ void gll16(const void* g, void* s) {
  __builtin_amdgcn_global_load_lds((as1_t)g, (as3_t)s, 16, 0, 0);
}

#define LGKM0 do { asm volatile("s_waitcnt lgkmcnt(0)" ::: "memory"); \
                   __builtin_amdgcn_sched_barrier(0); } while (0)

// ---------------- gate: logits fp32, top-4, softmax, bucket scatter + A-pack ----------------
__global__ __launch_bounds__(256) void k_gate(
    const float* __restrict__ x, const float* __restrict__ gw,
    unsigned short* __restrict__ xg, int* __restrict__ counts,
    float* __restrict__ bscore, int* __restrict__ tpos)
{
  __shared__ float xs[8][1024];
  __shared__ float lg[8][48];
  __shared__ int tp_s[32];
  const int tid = threadIdx.x;
  const int t0 = blockIdx.x * 8;
  for (int u = tid; u < 2048; u += 256) {
    int tok = u >> 8;
    int c = (u & 255) << 2;
    float4 v = *(const float4*)(x + (size_t)(t0 + tok) * DD + c);
    *(float4*)&xs[tok][c] = v;
  }
  __syncthreads();
  const int lane = tid & 63, wid = tid >> 6;
  for (int li = 0; li < 12; ++li) {
    const int l = wid + (li << 2);
    const float4* gp = (const float4*)(gw + (size_t)l * DD);
    float4 g0 = gp[lane], g1 = gp[lane + 64], g2 = gp[lane + 128], g3 = gp[lane + 192];
    for (int tok = 0; tok < 8; ++tok) {
      const float4* xp = (const float4*)&xs[tok][0];
      float4 a0 = xp[lane], a1 = xp[lane + 64], a2 = xp[lane + 128], a3 = xp[lane + 192];
      float s = a0.x*g0.x + a0.y*g0.y + a0.z*g0.z + a0.w*g0.w
              + a1.x*g1.x + a1.y*g1.y + a1.z*g1.z + a1.w*g1.w
              + a2.x*g2.x + a2.y*g2.y + a2.z*g2.z + a2.w*g2.w
              + a3.x*g3.x + a3.y*g3.y + a3.z*g3.z + a3.w*g3.w;
      #pragma unroll
      for (int off = 32; off; off >>= 1) s += __shfl_down(s, off);
      if (lane == 0) lg[tok][l] = s;
    }
  }
  __syncthreads();
  if (tid < 8) {
    const int tok = tid;
    float v[4]; int id[4];
    unsigned long long taken = 0ull;
    for (int k = 0; k < 4; ++k) {
      float best = -3.4e38f; int bi = 0;
      for (int l = 0; l < 48; ++l) {
        float cand = lg[tok][l];
        if (!((taken >> l) & 1ull) && cand > best) { best = cand; bi = l; }
      }
      taken |= (1ull << bi); v[k] = best; id[k] = bi;
    }
    float e1 = expf(v[1] - v[0]);
    float e2 = expf(v[2] - v[0]);
    float e3 = expf(v[3] - v[0]);
    float inv = 1.0f / (1.0f + e1 + e2 + e3);
    float sc[4] = { inv, e1*inv, e2*inv, e3*inv };
    for (int k = 0; k < 4; ++k) {
      int pos = atomicAdd(&counts[id[k]], 1);
      bscore[id[k] * TT + pos] = sc[k];
      int dst = (pos < 256) ? (id[k] * 256 + pos) : SENT;
      tp_s[tok * 4 + k] = dst;
      tpos[((t0 + tok) << 2) | k] = dst;
    }
  }
  __syncthreads();
  for (int g = 0; g < 32; ++g) {
    int dst = tp_s[g];
    if (dst == SENT) continue;
    const float* src = xs[g >> 2];
    float a0 = src[tid * 4], a1 = src[tid * 4 + 1], a2 = src[tid * 4 + 2], a3 = src[tid * 4 + 3];
    uint2 pk; pk.x = pack2(a0, a1); pk.y = pack2(a2, a3);
    *(uint2*)(xg + (size_t)dst * DD + tid * 4) = pk;
  }
}

// ---------------- wconvT: Wt[l][e][d] bf16 <- W[l][d][e] f32, 128x128 tiles (r3-verified) --------
__global__ __launch_bounds__(256) void k_wconvT(const float* __restrict__ W,
                                                unsigned short* __restrict__ Wt)
{
  const int l = blockIdx.z, d0 = blockIdx.y * 128, e0 = blockIdx.x * 128;
  __shared__ unsigned short T[128][136];
  const float* src = W + (size_t)l * DD * DD;
  const int tid = threadIdx.x;
  #pragma unroll
  for (int i = 0; i < 16; ++i) {
    int fl = i * 256 + tid;
    int d = fl >> 5, e4 = fl & 31;
    float4 v = *(const float4*)(src + (size_t)(d0 + d) * DD + e0 + e4 * 4);
    #pragma unroll
    for (int j = 0; j < 4; ++j) {
      int e = e4 * 4 + j;
      int unit = (d >> 3) ^ (e & 7);
      float fv = (j == 0) ? v.x : (j == 1) ? v.y : (j == 2) ? v.z : v.w;
      T[e][unit * 8 + (d & 7)] = (unsigned short)f2bf(fv);
    }
  }
  __syncthreads();
  #pragma unroll
  for (int i2 = 0; i2 < 8; ++i2) {
    int uo = i2 * 256 + tid;
    int e = uo >> 4, ds = uo & 15;
    short8 s8 = *(const short8*)&T[e][(ds ^ (e & 7)) * 8];
    *(short8*)(Wt + ((size_t)l << 20) + (size_t)(e0 + e) * DD + d0 + ds * 8) = s8;
  }
}

// ---------------- expert GEMM: BM=256, BN=64, BK=32, 256 thr (4 waves, 64-row tiles each) --------
// 3-deep LDS ring (A 16KB + B 4KB per buf = 60KB), prefetch distance 2, counted vmcnt(5)/iter,
// ONE s_barrier/iter. 64B LDS rows -> all ds_read_b128 frag reads bank-balanced with NO swizzle.
// Grid 768 (l = bid%48 -> an expert's 16 n-tiles share an XCD); 2 blocks/CU.
__global__ __launch_bounds__(256, 2) void k_expert(
    const unsigned short* __restrict__ xg, const unsigned short* __restrict__ Wt,
    const int* __restrict__ counts, const float* __restrict__ bscore,
    float* __restrict__ selp)
{
  const int bid = blockIdx.x;
  const int l = bid % LL;
  const int n0 = (bid / LL) * 64;
  const int ncnt = min(counts[l], 256);
  const int tid = threadIdx.x, lane = tid & 63, wr = tid >> 6;
  const int fr = lane & 15, fq = lane >> 4;

  __shared__ unsigned short As[3][256][32];   // 48 KB
  __shared__ unsigned short Bs[3][64][32];    // 12 KB
  __shared__ float scs[256];
  scs[tid] = (tid < ncnt) ? bscore[l * TT + tid] : 0.f;
  // (loop barriers order this write before epilogue reads)

  // A staging: units u = i*256+tid -> row u>>2, 16B col u&3 (lane-linear LDS dest per gll16)
  const unsigned short* axg = xg + ((size_t)l << 18);
  const size_t a0s = (size_t)((0 * 256 + tid) >> 2) * DD + ((0 * 256 + tid) & 3) * 8;
  const size_t a1s = (size_t)((1 * 256 + tid) >> 2) * DD + ((1 * 256 + tid) & 3) * 8;
  const size_t a2s = (size_t)((2 * 256 + tid) >> 2) * DD + ((2 * 256 + tid) & 3) * 8;
  const size_t a3s = (size_t)((3 * 256 + tid) >> 2) * DD + ((3 * 256 + tid) & 3) * 8;
  const int a0d = (0 * 256 + tid) * 8, a1d = (1 * 256 + tid) * 8;
  const int a2d = (2 * 256 + tid) * 8, a3d = (3 * 256 + tid) * 8;
  // B staging: unit tid -> row tid>>2 (0..63), col tid&3
  const unsigned short* bxg = Wt + ((size_t)l << 20) + (size_t)n0 * DD;
  const size_t bsc = (size_t)(tid >> 2) * DD + (tid & 3) * 8;
  const int bdd = tid * 8;

  f32x4 acc[4][4];
  #pragma unroll
  for (int m = 0; m < 4; ++m)
    #pragma unroll
    for (int n = 0; n < 4; ++n)
      #pragma unroll
      for (int j = 0; j < 4; ++j) acc[m][n][j] = 0.f;

#define STG_A01(BF, TC) do { \
    gll16(axg + a0s + (TC) * 32, (unsigned short*)As[BF] + a0d); \
    gll16(axg + a1s + (TC) * 32, (unsigned short*)As[BF] + a1d); } while (0)
#define STG_A23B(BF, TC) do { \
    gll16(axg + a2s + (TC) * 32, (unsigned short*)As[BF] + a2d); \
    gll16(axg + a3s + (TC) * 32, (unsigned short*)As[BF] + a3d); \
    gll16(bxg + bsc + (TC) * 32, (unsigned short*)Bs[BF] + bdd); } while (0)

#define E_ITER(BR, BF, TC, STGON, WN) do { \
    asm volatile("s_waitcnt vmcnt(" #WN ")" ::: "memory"); \
    __builtin_amdgcn_sched_barrier(0); \
    __builtin_amdgcn_s_barrier(); \
    __builtin_amdgcn_sched_barrier(0); \
    short8 bf0 = *(const short8*)&Bs[BR][ 0 + fr][fq * 8]; \
    short8 bf1 = *(const short8*)&Bs[BR][16 + fr][fq * 8]; \
    short8 bf2 = *(const short8*)&Bs[BR][32 + fr][fq * 8]; \
    short8 bf3 = *(const short8*)&Bs[BR][48 + fr][fq * 8]; \
    short8 a0 = *(const short8*)&As[BR][wr * 64 +  0 + fr][fq * 8]; \
    short8 a1 = *(const short8*)&As[BR][wr * 64 + 16 + fr][fq * 8]; \
    if (STGON) STG_A01(BF, TC); \
    LGKM0; \
    __builtin_amdgcn_s_setprio(1); \
    acc[0][0] = __builtin_amdgcn_mfma_f32_16x16x32_bf16(a0, bf0, acc[0][0], 0, 0, 0); \
    acc[0][1] = __builtin_amdgcn_mfma_f32_16x16x32_bf16(a0, bf1, acc[0][1], 0, 0, 0); \
    acc[0][2] = __builtin_amdgcn_mfma_f32_16x16x32_bf16(a0, bf2, acc[0][2], 0, 0, 0); \
    acc[0][3] = __builtin_amdgcn_mfma_f32_16x16x32_bf16(a0, bf3, acc[0][3], 0, 0, 0); \
    acc[1][0] = __builtin_amdgcn_mfma_f32_16x16x32_bf16(a1, bf0, acc[1][0], 0, 0, 0); \
    acc[1][1] = __builtin_amdgcn_mfma_f32_16x16x32_bf16(a1, bf1, acc[1][1], 0, 0, 0); \
    acc[1][2] = __builtin_amdgcn_mfma_f32_16x16x32_bf16(a1, bf2, acc[1][2], 0, 0, 0); \
    acc[1][3] = __builtin_amdgcn_mfma_f32_16x16x32_bf16(a1, bf3, acc[1][3], 0, 0, 0); \
    __builtin_amdgcn_s_setprio(0); \
    short8 a2 = *(const short8*)&As[BR][wr * 64 + 32 + fr][fq * 8]; \
    short8 a3 = *(const short8*)&As[BR][wr * 64 + 48 + fr][fq * 8]; \
    if (STGON) STG_A23B(BF, TC); \
    LGKM0; \
    __builtin_amdgcn_s_setprio(1); \
    acc[2][0] = __builtin_amdgcn_mfma_f32_16x16x32_bf16(a2, bf0, acc[2][0], 0, 0, 0); \
    acc[2][1] = __builtin_amdgcn_mfma_f32_16x16x32_bf16(a2, bf1, acc[2][1], 0, 0, 0); \
    acc[2][2] = __builtin_amdgcn_mfma_f32_16x16x32_bf16(a2, bf2, acc[2][2], 0, 0, 0); \
    acc[2][3] = __builtin_amdgcn_mfma_f32_16x16x32_bf16(a2, bf3, acc[2][3], 0, 0, 0); \
    acc[3][0] = __builtin_amdgcn_mfma_f32_16x16x32_bf16(a3, bf0, acc[3][0], 0, 0, 0); \
    acc[3][1] = __builtin_amdgcn_mfma_f32_16x16x32_bf16(a3, bf1, acc[3][1], 0, 0, 0); \
    acc[3][2] = __builtin_amdgcn_mfma_f32_16x16x32_bf16(a3, bf2, acc[3][2], 0, 0, 0); \
    acc[3][3] = __builtin_amdgcn_mfma_f32_16x16x32_bf16(a3, bf3, acc[3][3], 0, 0, 0); \
    __builtin_amdgcn_s_setprio(0); \
  } while (0)

  // prologue: stage tiles 0,1 (5 loads each)
  STG_A01(0, 0); STG_A23B(0, 0);
  STG_A01(1, 1); STG_A23B(1, 1);
  // steady: t = 0..29 (ring: read t%3, stage t+2 -> (t+2)%3), counted vmcnt(5)
  for (int tt = 0; tt < 30; tt += 3) {
    E_ITER(0, 2, tt + 2, 1, 5);
    E_ITER(1, 0, tt + 3, 1, 5);
    E_ITER(2, 1, tt + 4, 1, 5);
  }
  // tail: t=30 (buf 0; tile31 still in flight), t=31 (buf 1; drain)
  E_ITER(0, 0, 0, 0, 5);
  E_ITER(1, 0, 0, 0, 0);

#undef STG_A01
#undef STG_A23B
#undef E_ITER

  // epilogue: D[r][c]: c = lane&15 (e), r = (lane>>4)*4 + j  [m89-verified]
  #pragma unroll
  for (int m = 0; m < 4; ++m) {
    #pragma unroll
    for (int j = 0; j < 4; ++j) {
      const int r = wr * 64 + m * 16 + fq * 4 + j;
      if (r < ncnt) {
        const float sc = scs[r];
        float* op = selp + (size_t)(l * 256 + r) * DD + n0 + fr;
        #pragma unroll
        for (int n = 0; n < 4; ++n) op[n * 16] = acc[m][n][j] * sc;
      }
    }
  }
}

// ---------------- combine: lat_bf16[t][d] = sum_k selp[tpos[t*4+k]][d] ----------------
__global__ __launch_bounds__(256) void k_combine(const float* __restrict__ selp,
    const int* __restrict__ tpos, unsigned short* __restrict__ lat)
{
  const size_t i = ((size_t)blockIdx.x * 256 + threadIdx.x) << 2;
  const size_t t = i >> 10, d = i & 1023;
  int4 tp = *(const int4*)(tpos + (t << 2));
  float4 s0 = *(const float4*)(selp + (size_t)tp.x * DD + d);
  float4 s1 = *(const float4*)(selp + (size_t)tp.y * DD + d);
  float4 s2 = *(const float4*)(selp + (size_t)tp.z * DD + d);
  float4 s3 = *(const float4*)(selp + (size_t)tp.w * DD + d);
  float r0 = s0.x + s1.x + s2.x + s3.x;
  float r1 = s0.y + s1.y + s2.y + s3.y;
  float r2 = s0.z + s1.z + s2.z + s3.z;
  float r3 = s0.w + s1.w + s2.w + s3.w;
  uint2 pk; pk.x = pack2(r0, r1); pk.y = pack2(r2, r3);
  *(uint2*)(lat + i) = pk;
}

// ---------------- out_proj: y = x + lat @ out_w^T + b  (BM=128,BN=64, reg-staged dbuf) ----------------
__global__ __launch_bounds__(256, 2) void k_outproj(
    const unsigned short* __restrict__ lat, const float* __restrict__ W2,
    const float* __restrict__ xres, const float* __restrict__ bias,
    float* __restrict__ y)
{
  const int n0 = blockIdx.x * 64;
  const int m0 = blockIdx.y * 128;
  const int tid = threadIdx.x, lane = tid & 63, wid = tid >> 6;

  __shared__ alignas(16) unsigned short As[2][128][40];
  __shared__ alignas(16) unsigned short Bs[2][64][40];

  const int aq = tid >> 2, aseg = tid & 3;
  const unsigned short* la0 = lat + (size_t)(m0 + aq) * DD + aseg * 8;
  const unsigned short* la1 = lat + (size_t)(m0 + aq + 64) * DD + aseg * 8;
  const int be = tid >> 2, bks = tid & 3;
  const float* wb = W2 + (size_t)(n0 + be) * DD + bks * 8;

  f32x4 acc[2][4];
  #pragma unroll
  for (int m = 0; m < 2; ++m)
    #pragma unroll
    for (int n = 0; n < 4; ++n)
      #pragma unroll
      for (int j = 0; j < 4; ++j) acc[m][n][j] = 0.f;

  int4 av0, av1;
  float4 w0, w1;

#define O_LOAD(kk) do { \
    av0 = *(const int4*)(la0 + (kk)); \
    av1 = *(const int4*)(la1 + (kk)); \
    w0 = *(const float4*)(wb + (kk)); \
    w1 = *(const float4*)(wb + (kk) + 4); \
  } while (0)

#define O_STORE(b) do { \
    *(int4*)&As[b][aq][aseg * 8]      = av0; \
    *(int4*)&As[b][aq + 64][aseg * 8] = av1; \
    uint4 pv; \
    pv.x = pack2(w0.x, w0.y); pv.y = pack2(w0.z, w0.w); \
    pv.z = pack2(w1.x, w1.y); pv.w = pack2(w1.z, w1.w); \
    *(uint4*)&Bs[b][be][bks * 8] = pv; \
  } while (0)

  O_LOAD(0); O_STORE(0); __syncthreads();
  int cur = 0;
  for (int t = 0; t < 32; ++t) {
    const bool more = (t < 31);
    if (more) O_LOAD((t + 1) * 32);
    short8 af[2], bf[4];
    #pragma unroll
    for (int n = 0; n < 4; ++n)
      bf[n] = *(const short8*)&Bs[cur][n * 16 + (lane & 15)][(lane >> 4) * 8];
    #pragma unroll
    for (int m = 0; m < 2; ++m)
      af[m] = *(const short8*)&As[cur][wid * 32 + m * 16 + (lane & 15)][(lane >> 4) * 8];
    #pragma unroll
    for (int m = 0; m < 2; ++m)
      #pragma unroll
      for (int n = 0; n < 4; ++n)
        acc[m][n] = __builtin_amdgcn_mfma_f32_16x16x32_bf16(af[m], bf[n], acc[m][n], 0, 0, 0);
    if (more) O_STORE(cur ^ 1);
    __syncthreads();
    cur ^= 1;
  }
#undef O_LOAD
#undef O_STORE

  #pragma unroll
  for (int m = 0; m < 2; ++m) {
    #pragma unroll
    for (int j = 0; j < 4; ++j) {
      const int t = m0 + wid * 32 + m * 16 + ((lane >> 4) << 2) + j;
      #pragma unroll
      for (int n = 0; n < 4; ++n) {
        const int e = n0 + n * 16 + (lane & 15);
        y[(size_t)t * DD + e] = xres[(size_t)t * DD + e] + acc[m][n][j] + bias[e];
      }
    }
  }
}

// ---------------- LayerNorm ----------------
__global__ __launch_bounds__(256) void k_ln(const float* __restrict__ y,
    const float* __restrict__ g, const float* __restrict__ b, float* __restrict__ out)
{
  const int t = blockIdx.x, tid = threadIdx.x;
  float4 v = *(const float4*)(y + (size_t)t * DD + tid * 4);
  float s  = v.x + v.y + v.z + v.w;
  float ss = v.x*v.x + v.y*v.y + v.z*v.z + v.w*v.w;
  #pragma unroll
  for (int off = 32; off; off >>= 1) { s += __shfl_down(s, off); ss += __shfl_down(ss, off); }
  __shared__ float rs[8];
  const int wid = tid >> 6, lane = tid & 63;
  if (lane == 0) { rs[wid] = s; rs[wid + 4] = ss; }
  __syncthreads();
  float S  = rs[0] + rs[1] + rs[2] + rs[3];
  float SS = rs[4] + rs[5] + rs[6] + rs[7];
  float mu = S * (1.0f / DD);
  float var = SS * (1.0f / DD) - mu * mu;
  float inv = rsqrtf(var + 1e-5f);
  float4 gg = *(const float4*)(g + tid * 4);
  float4 bb = *(const float4*)(b + tid * 4);
  float4 o;
  o.x = gg.x * (v.x - mu) * inv + bb.x;
  o.y = gg.y * (v.y - mu) * inv + bb.y;
  o.z = gg.z * (v.z - mu) * inv + bb.z;
  o.w = gg.w * (v.w - mu) * inv + bb.w;
  *(float4*)(out + (size_t)t * DD + tid * 4) = o;
}

extern "C" void kernel_launch(void* const* d_in, const int* in_sizes, int n_in,
                              void* d_out, int out_size, void* d_ws, size_t ws_size,
                              hipStream_t stream) {
  (void)in_sizes; (void)n_in; (void)out_size;
  const float* x   = (const float*)d_in[0];
  const float* gw  = (const float*)d_in[1];
  const float* lw  = (const float*)d_in[2];
  const float* ow  = (const float*)d_in[3];
  const float* obv = (const float*)d_in[4];
  const float* lng = (const float*)d_in[5];
  const float* lnb = (const float*)d_in[6];
  float* out = (float*)d_out;
  char* ws = (char*)d_ws;

  // layout: xg 24MB @0 | selp 48MB+4K @24M | lat @73M | y @77M | counts @85M | bscore | tpos @86M
  //         Wt 96MB @96M..192M
  unsigned short* xg     = (unsigned short*)(ws);
  float*          selp   = (float*)(ws + (24ull << 20));
  unsigned short* lat    = (unsigned short*)(ws + (73ull << 20));
  float*          y      = (float*)(ws + (77ull << 20));
  int*            counts = (int*)(ws + (85ull << 20));
  float*          bscore = (float*)(ws + (85ull << 20) + 4096);
  int*            tpos   = (int*)(ws + (86ull << 20));
  unsigned short* Wt     = (unsigned short*)(ws + (96ull << 20));
  if (ws_size < (193ull << 20)) return;   // loud failure

  hipMemsetAsync(counts, 0, LL * sizeof(int), stream);
  hipMemsetAsync(selp + (size_t)SENT * DD, 0, DD * sizeof(float), stream);  // sentinel row
  k_gate<<<TT / 8, 256, 0, stream>>>(x, gw, xg, counts, bscore, tpos);
  k_wconvT<<<dim3(8, 8, LL), 256, 0, stream>>>(lw, Wt);
  k_expert<<<768, 256, 0, stream>>>(xg, Wt, counts, bscore, selp);
  k_combine<<<TT * DD / (256 * 4), 256, 0, stream>>>(selp, tpos, lat);
  k_outproj<<<dim3(16, 16), 256, 0, stream>>>(lat, ow, x, obv, y);
  k_ln<<<TT, 256, 0, stream>>>(y, lng, lnb, out);
}